// Round 15
// baseline (197.459 us; speedup 1.0000x reference)
//
#include <hip/hip_runtime.h>
#include <hip/hip_bf16.h>
#include <cstdint>

using bf16x8 = __attribute__((ext_vector_type(8))) __bf16;
using f32x4  = __attribute__((ext_vector_type(4))) float;

#define LOG2E 1.4426950408889634f

__device__ inline void gload16(__bf16* lds, const __bf16* g) {
    __builtin_amdgcn_global_load_lds((const __attribute__((address_space(1))) void*)g,
                                     (__attribute__((address_space(3))) void*)lds, 16, 0, 0);
}
__device__ inline void wait_barrier4() {
    asm volatile("s_waitcnt vmcnt(4)" ::: "memory");
    __builtin_amdgcn_s_barrier();
}
__device__ inline void wait_barrier0() {
    asm volatile("s_waitcnt vmcnt(0)" ::: "memory");
    __builtin_amdgcn_s_barrier();
}

// ---------------------------------------------------------------------------
// RMSNorm: one block (256 threads) per row of 1024 fp32 -> bf16
// ---------------------------------------------------------------------------
__global__ __launch_bounds__(256) void rmsnorm_kernel(const float* __restrict__ x,
                                                      const float* __restrict__ w,
                                                      __bf16* __restrict__ xn) {
    const int row = blockIdx.x;
    const float4 v = reinterpret_cast<const float4*>(x + (size_t)row * 1024)[threadIdx.x];
    float ss = v.x * v.x + v.y * v.y + v.z * v.z + v.w * v.w;
#pragma unroll
    for (int i = 1; i < 64; i <<= 1) ss += __shfl_xor(ss, i);
    __shared__ float part[4];
    if ((threadIdx.x & 63) == 0) part[threadIdx.x >> 6] = ss;
    __syncthreads();
    const float total = part[0] + part[1] + part[2] + part[3];
    const float scale = rsqrtf(total * (1.0f / 1024.0f) + 1.1920929e-07f);
    const float4 wv = reinterpret_cast<const float4*>(w)[threadIdx.x];
    union { __bf16 h[4]; uint2 u; } pk;
    pk.h[0] = (__bf16)(v.x * scale * wv.x);
    pk.h[1] = (__bf16)(v.y * scale * wv.y);
    pk.h[2] = (__bf16)(v.z * scale * wv.z);
    pk.h[3] = (__bf16)(v.w * scale * wv.w);
    reinterpret_cast<uint2*>(xn + (size_t)row * 1024)[threadIdx.x] = pk.u;
}

// ---------------------------------------------------------------------------
// Transpose + cast: in (K x N) fp32 row-major -> out (N x K) bf16 row-major
// ---------------------------------------------------------------------------
__global__ void transpose_cast_kernel(const float* __restrict__ in,
                                      __bf16* __restrict__ out, int K, int N) {
    __shared__ float tile[32][33];
    const int n0 = blockIdx.x * 32, k0 = blockIdx.y * 32;
#pragma unroll
    for (int r = threadIdx.y; r < 32; r += 8)
        tile[r][threadIdx.x] = in[(size_t)(k0 + r) * N + n0 + threadIdx.x];
    __syncthreads();
#pragma unroll
    for (int r = threadIdx.y; r < 32; r += 8)
        out[(size_t)(n0 + r) * K + k0 + threadIdx.x] = (__bf16)tile[threadIdx.x][r];
}

// ---------------------------------------------------------------------------
// cos/sin table: csin[pos*64+d] = (cos, sin) of rot[pos][d]. 262144 entries.
// ---------------------------------------------------------------------------
__global__ __launch_bounds__(256) void csin_kernel(const float* __restrict__ rot,
                                                   float2* __restrict__ csin) {
    const int i = blockIdx.x * 256 + threadIdx.x;
    float s, c;
    sincosf(rot[i], &s, &c);
    csin[i] = make_float2(c, s);
}

// ---------------------------------------------------------------------------
// RoPE (table-based) in-place on the K half of qk [8192][1024] only
// (Q rope is fused into attn's register Q load). One wave per (b,pos).
// ---------------------------------------------------------------------------
__global__ __launch_bounds__(256) void rope_k_kernel(__bf16* __restrict__ qk,
                                                     const float2* __restrict__ csin) {
    const int row = blockIdx.x * 4 + (threadIdx.x >> 6);   // b*4096+pos
    const int lane = threadIdx.x & 63;
    const int h = lane >> 3, dl = (lane & 7) * 4;
    const int pos = row & 4095;
    const float4 csA = *reinterpret_cast<const float4*>(&csin[pos * 64 + dl]);
    const float4 csB = *reinterpret_cast<const float4*>(&csin[pos * 64 + dl + 2]);
    const float4 csC = *reinterpret_cast<const float4*>(&csin[pos * 64 + dl + 32]);
    const float4 csD = *reinterpret_cast<const float4*>(&csin[pos * 64 + dl + 34]);
    const float c0[4] = {csA.x, csA.z, csB.x, csB.z};
    const float s0[4] = {csA.y, csA.w, csB.y, csB.w};
    const float c1[4] = {csC.x, csC.z, csD.x, csD.z};
    const float s1[4] = {csC.y, csC.w, csD.y, csD.w};
    __bf16* pp = qk + (size_t)row * 1024 + 512 + h * 64 + dl;
    union { uint2 u; __bf16 hh[4]; } va, vb, oa, ob;
    va.u = *reinterpret_cast<const uint2*>(pp);
    vb.u = *reinterpret_cast<const uint2*>(pp + 32);
#pragma unroll
    for (int j = 0; j < 4; ++j) {
        const float a = (float)va.hh[j], b2 = (float)vb.hh[j];
        oa.hh[j] = (__bf16)(a * c0[j] - b2 * s0[j]);
        ob.hh[j] = (__bf16)(b2 * c1[j] + a * s1[j]);
    }
    *reinterpret_cast<uint2*>(pp)      = oa.u;
    *reinterpret_cast<uint2*>(pp + 32) = ob.u;
}

// ---------------------------------------------------------------------------
// GEMM: C(MxN) = A(MxK) @ Bt(NxK)^T, bf16 in, fp32 accum.
// Ring-3 LDS, counted vmcnt(4) barriers, bijective XCD swizzle.
// MODE 0: float output, ld = N. MODE 1 (QKV): cols <1024 -> qk buf
// [8192][1024] bf16 (raw q/k); v -> vt[1024][4096] transposed + kappa.
// ---------------------------------------------------------------------------
template <typename OutT, int MODE>
__global__ __launch_bounds__(256) void gemm_bt(const __bf16* __restrict__ A,
                                               const __bf16* __restrict__ Bt,
                                               OutT* __restrict__ C,
                                               __bf16* __restrict__ vt,
                                               int M, int N, int K) {
    __shared__ __align__(16) __bf16 As[3][128 * 32];
    __shared__ __align__(16) __bf16 Bs[3][128 * 32];
    const int nbn = N >> 7;
    const int xcd = blockIdx.x & 7;
    const int idx = blockIdx.x >> 3;
    const int bm = xcd * 8 + idx / nbn;
    const int bn = idx % nbn;
    const int tid = threadIdx.x;
    const int w = tid >> 6, l = tid & 63, lg = l >> 4, lr = l & 15;
    const int wr = w >> 1, wc = w & 1;
    const __bf16* Ab = A + (size_t)(bm * 128) * K;
    const __bf16* Bb = Bt + (size_t)(bn * 128) * K;
    const int srow = tid >> 2, scol = (tid & 3) * 8;
    const __bf16* Asrc = Ab + (size_t)srow * K + scol;
    const __bf16* Bsrc = Bb + (size_t)srow * K + scol;

    auto stage = [&](int k2) {
        const int nx = k2 % 3;
        const int off = k2 * 32;
        gload16(&As[nx][tid * 8],        Asrc + off);
        gload16(&As[nx][2048 + tid * 8], Asrc + (size_t)64 * K + off);
        gload16(&Bs[nx][tid * 8],        Bsrc + off);
        gload16(&Bs[nx][2048 + tid * 8], Bsrc + (size_t)64 * K + off);
    };

    const int NS = K >> 5;
    f32x4 acc[4][4] = {};
    stage(0);
    stage(1);
    wait_barrier4();
    for (int k = 0; k < NS; ++k) {
        const bool more = (k + 2 < NS);
        if (more) stage(k + 2);
        const __bf16* Ac = &As[k % 3][0];
        const __bf16* Bc = &Bs[k % 3][0];
        bf16x8 af[4], bfr[4];
#pragma unroll
        for (int m = 0; m < 4; ++m)
            af[m] = *reinterpret_cast<const bf16x8*>(Ac + (wr * 64 + m * 16 + lr) * 32 + lg * 8);
#pragma unroll
        for (int nn = 0; nn < 4; ++nn)
            bfr[nn] = *reinterpret_cast<const bf16x8*>(Bc + (wc * 64 + nn * 16 + lr) * 32 + lg * 8);
#pragma unroll
        for (int m = 0; m < 4; ++m)
#pragma unroll
            for (int nn = 0; nn < 4; ++nn)
                acc[m][nn] = __builtin_amdgcn_mfma_f32_16x16x32_bf16(af[m], bfr[nn],
                                                                     acc[m][nn], 0, 0, 0);
        if (more) wait_barrier4();
        else      wait_barrier0();
    }
    if constexpr (MODE == 1) {
        const int cb = bn * 128 + wc * 64;
        if (cb < 1024) {                          // q,k -> qk buf (ld 1024)
#pragma unroll
            for (int m = 0; m < 4; ++m) {
                const int rg = bm * 128 + wr * 64 + m * 16 + 4 * lg;
#pragma unroll
                for (int nn = 0; nn < 4; ++nn) {
                    const int cg = cb + nn * 16 + lr;
#pragma unroll
                    for (int r = 0; r < 4; ++r)
                        C[(size_t)(rg + r) * 1024 + cg] = (OutT)acc[m][nn][r];
                }
            }
        } else {                                  // v -> vt transposed + kappa
#pragma unroll
            for (int m = 0; m < 4; ++m) {
                const int rg = bm * 128 + wr * 64 + m * 16 + 4 * lg;
                const int bidx = rg >> 12, pos0 = rg & 4095;
                const int a0 = pos0 & 63;
                const int cp = 32 * (a0 >> 5) + 8 * ((a0 >> 2) & 3) + 4 * ((a0 >> 4) & 1);
                const int nbase = (pos0 & ~63) + cp;
#pragma unroll
                for (int nn = 0; nn < 4; ++nn) {
                    const int col = cb + nn * 16 + lr - 1024;
                    const int hh = col >> 6, dd = col & 63;
                    union { __bf16 h4[4]; uint2 u; } pk2;
#pragma unroll
                    for (int r = 0; r < 4; ++r) pk2.h4[r] = (__bf16)acc[m][nn][r];
                    *reinterpret_cast<uint2*>(&vt[((size_t)(bidx * 8 + hh) * 64 + dd) * 4096 + nbase]) = pk2.u;
                }
            }
        }
        return;
    }
#pragma unroll
    for (int m = 0; m < 4; ++m) {
        const int rg = bm * 128 + wr * 64 + m * 16 + 4 * lg;
#pragma unroll
        for (int nn = 0; nn < 4; ++nn) {
            const int cg = bn * 128 + wc * 64 + nn * 16 + lr;
#pragma unroll
            for (int r = 0; r < 4; ++r)
                C[(size_t)(rg + r) * N + cg] = (OutT)acc[m][nn][r];
        }
    }
}

// ---------------------------------------------------------------------------
// Causal flash attention v15: 32 q-rows per WAVE (nt=0,1) -> each K/V LDS
// fragment feeds 2x the MFMAs, halving per-CU LDS-read traffic (which was
// ~68% of wall at R14: 16 waves x 33 tiles x 16KB / 85B/cyc ~= 41us).
// 512 blocks x 256 thr (4 waves x 32 rows, QBLK=128). Per-XCD ordering:
// j<32 -> (head0, qt=31-j), j>=32 -> (head1, qt=j-32): under breadth-first
// CU fill each CU's two blocks have complementary qt (sum 31) -> balanced.
// Ring-3 K/V (48KB, 2 blocks/CU at ~150 VGPR), unroll x6 static, fused
// Q-rope, ones-Lacc (Lacc[nt][0] = full row-sum), zero-VALU staging.
// ---------------------------------------------------------------------------
__global__ __launch_bounds__(256) void attn_kernel(const __bf16* __restrict__ qkp,
                                                   const __bf16* __restrict__ vt,
                                                   const float2* __restrict__ csin,
                                                   __bf16* __restrict__ attn_out) {
    const int bid = blockIdx.x;                      // 512 blocks
    const int xcd = bid & 7;
    const int j = bid >> 3;                          // 0..63 per XCD
    const int hs = j >> 5;                           // 0 | 1
    const int qt = hs ? (j - 32) : (31 - j);         // complementary pairing
    const int bh = 2 * xcd + hs;
    const int b = bh >> 3, h = bh & 7;
    const int tid = threadIdx.x;
    const int w = tid >> 6, l = tid & 63, lg = l >> 4, lr = l & 15;

    __shared__ __align__(16) __bf16 Ks[3][64 * 64];
    __shared__ __align__(16) __bf16 Vs[3][64 * 64];

    const __bf16* qbase = qkp + (size_t)b * 4096 * 1024 + h * 64;
    const __bf16* kbase = qbase + 512;
    const __bf16* vtb   = vt + (size_t)(b * 8 + h) * 64 * 4096;

    const int sr = tid >> 3;
    const int sc = ((tid & 7) ^ (sr & 7)) * 8;
    const __bf16* kp = kbase + (size_t)sr * 1024 + sc;
    const __bf16* vp = vtb + (size_t)sr * 4096 + sc;

    const int xel = (lr & 7) * 8;                    // read-side swizzle

    const int wq0 = qt * 128 + 32 * w;               // wave owns rows wq0..wq0+31
    const int nkt = 2 * qt + 2;

    auto stage2 = [&](__bf16* kdst, __bf16* vdst) {
        gload16(kdst + tid * 8,         kp);
        gload16(kdst + (tid + 256) * 8, kp + 32 * 1024);
        gload16(vdst + tid * 8,         vp);
        gload16(vdst + (tid + 256) * 8, vp + 32 * 4096);
        kp += 64 * 1024;
        vp += 64;
    };

    // prologue part 1: start staging tiles 0,1 (fly under Q-rope VALU)
    stage2(Ks[0], Vs[0]);
    stage2(Ks[1], Vs[1]);

    // Q load + fused rope (+ 1/sqrt(d) * log2e) for both 16-row sub-tiles
    bf16x8 Qf[2][2];
#pragma unroll
    for (int nt = 0; nt < 2; ++nt) {
        const int qrow = wq0 + 16 * nt + lr;
        const __bf16* qp = qbase + (size_t)qrow * 1024 + 8 * lg;
        const bf16x8 rq0 = *reinterpret_cast<const bf16x8*>(qp);
        const bf16x8 rq1 = *reinterpret_cast<const bf16x8*>(qp + 32);
        const float2* csp = csin + (size_t)qrow * 64 + 8 * lg;
        const float qs = 0.125f * LOG2E;
#pragma unroll
        for (int i = 0; i < 8; ++i) {
            const float2 ca = csp[i];
            const float2 cb = csp[i + 32];
            const float a = (float)rq0[i], b2 = (float)rq1[i];
            Qf[nt][0][i] = (__bf16)((a * ca.x - b2 * ca.y) * qs);
            Qf[nt][1][i] = (__bf16)((b2 * cb.x + a * cb.y) * qs);
        }
    }

    bf16x8 ones;
#pragma unroll
    for (int i = 0; i < 8; ++i) ones[i] = (__bf16)1.0f;

    f32x4 O[2][4] = {};
    f32x4 Lacc[2] = {};
    float m_[2] = {-1e30f, -1e30f};

    auto qk_step = [&](f32x4 (&S)[2][4], const __bf16* kb) {
        __builtin_amdgcn_s_setprio(1);
#pragma unroll
        for (int jt = 0; jt < 4; ++jt) {
            const __bf16* kr = kb + (16 * jt + lr) * 64;
            const bf16x8 Kf0 = *reinterpret_cast<const bf16x8*>(kr + ((8 * lg) ^ xel));
            const bf16x8 Kf1 = *reinterpret_cast<const bf16x8*>(kr + ((32 + 8 * lg) ^ xel));
#pragma unroll
            for (int nt = 0; nt < 2; ++nt) {
                f32x4 z = {};
                z = __builtin_amdgcn_mfma_f32_16x16x32_bf16(Kf0, Qf[nt][0], z, 0, 0, 0);
                S[nt][jt] = __builtin_amdgcn_mfma_f32_16x16x32_bf16(Kf1, Qf[nt][1], z, 0, 0, 0);
            }
        }
        __builtin_amdgcn_s_setprio(0);
    };
    auto smpv = [&](f32x4 (&SC)[2][4], const __bf16* vb, int kt0, bool tail) {
        bool act[2] = {true, true};
        if (tail) {
#pragma unroll
            for (int nt = 0; nt < 2; ++nt) {
                act[nt] = (64 * kt0 <= wq0 + 16 * nt + 15);
                if (act[nt] && 64 * kt0 + 63 > wq0 + 16 * nt) {
                    const int thr = wq0 + 16 * nt + lr - 64 * kt0;
#pragma unroll
                    for (int jt = 0; jt < 4; ++jt)
#pragma unroll
                        for (int r = 0; r < 4; ++r)
                            if (16 * jt + 4 * lg + r > thr) SC[nt][jt][r] = -1e30f;
                }
            }
        }
#pragma unroll
        for (int nt = 0; nt < 2; ++nt) {
            if (!act[nt]) continue;
            float mx = -1e30f;
#pragma unroll
            for (int jt = 0; jt < 4; ++jt)
                mx = fmaxf(mx, fmaxf(fmaxf(SC[nt][jt][0], SC[nt][jt][1]),
                                     fmaxf(SC[nt][jt][2], SC[nt][jt][3])));
            if (__any(mx > m_[nt] + 8.0f)) {
                mx = fmaxf(mx, __shfl_xor(mx, 16));
                mx = fmaxf(mx, __shfl_xor(mx, 32));
                const float mn = fmaxf(m_[nt], mx);
                const float alpha = __builtin_amdgcn_exp2f(m_[nt] - mn);
                m_[nt] = mn;
                Lacc[nt] *= alpha;
#pragma unroll
                for (int dt = 0; dt < 4; ++dt) O[nt][dt] *= alpha;
            }
#pragma unroll
            for (int jt = 0; jt < 4; ++jt)
#pragma unroll
                for (int r = 0; r < 4; ++r)
                    SC[nt][jt][r] = __builtin_amdgcn_exp2f(SC[nt][jt][r] - m_[nt]);
        }
        bf16x8 Pf[2][2];
#pragma unroll
        for (int nt = 0; nt < 2; ++nt)
            if (act[nt])
#pragma unroll
                for (int s = 0; s < 2; ++s)
#pragma unroll
                    for (int i = 0; i < 8; ++i)
                        Pf[nt][s][i] = (__bf16)SC[nt][2 * s + (i >> 2)][i & 3];
        __builtin_amdgcn_s_setprio(1);
#pragma unroll
        for (int nt = 0; nt < 2; ++nt)
            if (act[nt])
#pragma unroll
                for (int s = 0; s < 2; ++s)
                    Lacc[nt] = __builtin_amdgcn_mfma_f32_16x16x32_bf16(ones, Pf[nt][s], Lacc[nt], 0, 0, 0);
#pragma unroll
        for (int s = 0; s < 2; ++s)
#pragma unroll
            for (int dt = 0; dt < 4; ++dt) {
                const bf16x8 Vf = *reinterpret_cast<const bf16x8*>(
                    vb + (16 * dt + lr) * 64 + ((32 * s + 8 * lg) ^ xel));
                if (act[0]) O[0][dt] = __builtin_amdgcn_mfma_f32_16x16x32_bf16(Vf, Pf[0][s], O[0][dt], 0, 0, 0);
                if (act[1]) O[1][dt] = __builtin_amdgcn_mfma_f32_16x16x32_bf16(Vf, Pf[1][s], O[1][dt], 0, 0, 0);
            }
        __builtin_amdgcn_s_setprio(0);
    };

    f32x4 S0[2][4], S1[2][4];
    int t = 0;

    // prologue part 2: tiles 0,1 landed; S0 = QK(0)
    __syncthreads();
    qk_step(S0, Ks[0]);

    // main loop: 6 statically-indexed bodies, all pre-diagonal for all waves
    for (; t + 8 <= nkt; t += 6) {
        stage2(Ks[2], Vs[2]); qk_step(S1, Ks[1]); smpv(S0, Vs[0], t,     false); __syncthreads();
        stage2(Ks[0], Vs[0]); qk_step(S0, Ks[2]); smpv(S1, Vs[1], t + 1, false); __syncthreads();
        stage2(Ks[1], Vs[1]); qk_step(S1, Ks[0]); smpv(S0, Vs[2], t + 2, false); __syncthreads();
        stage2(Ks[2], Vs[2]); qk_step(S0, Ks[1]); smpv(S1, Vs[0], t + 3, false); __syncthreads();
        stage2(Ks[0], Vs[0]); qk_step(S1, Ks[2]); smpv(S0, Vs[1], t + 4, false); __syncthreads();
        stage2(Ks[1], Vs[1]); qk_step(S0, Ks[0]); smpv(S1, Vs[2], t + 5, false); __syncthreads();
    }

    // tail: <=7 tiles, dynamic ring indices, per-nt skip/mask near diagonal
    {
        f32x4 Sp[2][4];
#pragma unroll
        for (int nt = 0; nt < 2; ++nt)
#pragma unroll
            for (int jt = 0; jt < 4; ++jt) Sp[nt][jt] = S0[nt][jt];
        for (; t < nkt; ++t) {
            if (t + 2 < nkt) stage2(Ks[(t + 2) % 3], Vs[(t + 2) % 3]);
            f32x4 Sn[2][4];
            if (t + 1 < nkt) qk_step(Sn, Ks[(t + 1) % 3]);
            smpv(Sp, Vs[t % 3], t, true);
            __syncthreads();
#pragma unroll
            for (int nt = 0; nt < 2; ++nt)
#pragma unroll
                for (int jt = 0; jt < 4; ++jt) Sp[nt][jt] = Sn[nt][jt];
        }
    }

    // epilogue: Lacc[nt][0] is already the full row-sum (MFMA reduced)
#pragma unroll
    for (int nt = 0; nt < 2; ++nt) {
        const float inv = 1.0f / Lacc[nt][0];
        __bf16* op = attn_out + ((size_t)b * 4096 + wq0 + 16 * nt + lr) * 512 + h * 64;
#pragma unroll
        for (int dt = 0; dt < 4; ++dt) {
            union { __bf16 h4[4]; uint2 u; } ow;
#pragma unroll
            for (int r = 0; r < 4; ++r) ow.h4[r] = (__bf16)(O[nt][dt][r] * inv);
            *reinterpret_cast<uint2*>(op + 16 * dt + 4 * lg) = ow.u;
        }
    }
}

// ---------------------------------------------------------------------------
extern "C" void kernel_launch(void* const* d_in, const int* in_sizes, int n_in,
                              void* d_out, int out_size, void* d_ws, size_t ws_size,
                              hipStream_t stream) {
    (void)in_sizes; (void)n_in; (void)out_size; (void)ws_size;
    const float* x    = (const float*)d_in[0];
    const float* rot  = (const float*)d_in[1];
    const float* rmsw = (const float*)d_in[2];
    const float* wqkv = (const float*)d_in[3];
    const float* wout = (const float*)d_in[4];
    float* out = (float*)d_out;

    char* ws = (char*)d_ws;
    __bf16* xn    = (__bf16*)ws;                       // 16,777,216 B
    __bf16* wqkvt = (__bf16*)(ws + 16777216);          //  3,145,728 B
    __bf16* woutt = (__bf16*)(ws + 16777216 + 3145728);//  1,048,576 B
    __bf16* aout  = (__bf16*)(ws + 16777216 + 3145728 + 1048576); // 8,388,608 B
    // d_out during pipeline: qk [0,16.78M), csin [16.78M,18.87M),
    // vt [18.87M,27.26M) — all dead before the final GEMM overwrites d_out.
    __bf16* qk   = (__bf16*)d_out;
    float2* csin = (float2*)((char*)d_out + 16777216);
    __bf16* vt   = (__bf16*)((char*)d_out + 18874368);

    rmsnorm_kernel<<<8192, 256, 0, stream>>>(x, rmsw, xn);
    transpose_cast_kernel<<<dim3(48, 32), dim3(32, 8), 0, stream>>>(wqkv, wqkvt, 1024, 1536);
    transpose_cast_kernel<<<dim3(32, 16), dim3(32, 8), 0, stream>>>(wout, woutt, 512, 1024);
    csin_kernel<<<1024, 256, 0, stream>>>(rot, csin);
    gemm_bt<__bf16, 1><<<768, 256, 0, stream>>>(xn, wqkvt, qk, vt, 8192, 1536, 1024);
    rope_k_kernel<<<2048, 256, 0, stream>>>(qk, csin);
    attn_kernel<<<512, 256, 0, stream>>>(qk, vt, csin, aout);
    gemm_bt<float, 0><<<512, 256, 0, stream>>>(aout, woutt, out, nullptr, 8192, 1024, 512);
}

// Round 16
// 161.050 us; speedup vs baseline: 1.2261x; 1.2261x over previous
//
#include <hip/hip_runtime.h>
#include <hip/hip_bf16.h>
#include <cstdint>

using bf16x8 = __attribute__((ext_vector_type(8))) __bf16;
using f32x4  = __attribute__((ext_vector_type(4))) float;

#define LOG2E 1.4426950408889634f

__device__ inline void gload16(__bf16* lds, const __bf16* g) {
    __builtin_amdgcn_global_load_lds((const __attribute__((address_space(1))) void*)g,
                                     (__attribute__((address_space(3))) void*)lds, 16, 0, 0);
}
__device__ inline void wait_barrier4() {
    asm volatile("s_waitcnt vmcnt(4)" ::: "memory");
    __builtin_amdgcn_s_barrier();
}
__device__ inline void wait_barrier0() {
    asm volatile("s_waitcnt vmcnt(0)" ::: "memory");
    __builtin_amdgcn_s_barrier();
}

// ---------------------------------------------------------------------------
// RMSNorm: one block (256 threads) per row of 1024 fp32 -> bf16
// ---------------------------------------------------------------------------
__global__ __launch_bounds__(256) void rmsnorm_kernel(const float* __restrict__ x,
                                                      const float* __restrict__ w,
                                                      __bf16* __restrict__ xn) {
    const int row = blockIdx.x;
    const float4 v = reinterpret_cast<const float4*>(x + (size_t)row * 1024)[threadIdx.x];
    float ss = v.x * v.x + v.y * v.y + v.z * v.z + v.w * v.w;
#pragma unroll
    for (int i = 1; i < 64; i <<= 1) ss += __shfl_xor(ss, i);
    __shared__ float part[4];
    if ((threadIdx.x & 63) == 0) part[threadIdx.x >> 6] = ss;
    __syncthreads();
    const float total = part[0] + part[1] + part[2] + part[3];
    const float scale = rsqrtf(total * (1.0f / 1024.0f) + 1.1920929e-07f);
    const float4 wv = reinterpret_cast<const float4*>(w)[threadIdx.x];
    union { __bf16 h[4]; uint2 u; } pk;
    pk.h[0] = (__bf16)(v.x * scale * wv.x);
    pk.h[1] = (__bf16)(v.y * scale * wv.y);
    pk.h[2] = (__bf16)(v.z * scale * wv.z);
    pk.h[3] = (__bf16)(v.w * scale * wv.w);
    reinterpret_cast<uint2*>(xn + (size_t)row * 1024)[threadIdx.x] = pk.u;
}

// ---------------------------------------------------------------------------
// Transpose + cast: in (K x N) fp32 row-major -> out (N x K) bf16 row-major
// ---------------------------------------------------------------------------
__global__ void transpose_cast_kernel(const float* __restrict__ in,
                                      __bf16* __restrict__ out, int K, int N) {
    __shared__ float tile[32][33];
    const int n0 = blockIdx.x * 32, k0 = blockIdx.y * 32;
#pragma unroll
    for (int r = threadIdx.y; r < 32; r += 8)
        tile[r][threadIdx.x] = in[(size_t)(k0 + r) * N + n0 + threadIdx.x];
    __syncthreads();
#pragma unroll
    for (int r = threadIdx.y; r < 32; r += 8)
        out[(size_t)(n0 + r) * K + k0 + threadIdx.x] = (__bf16)tile[threadIdx.x][r];
}

// ---------------------------------------------------------------------------
// cos/sin table: csin[pos*64+d] = (cos, sin) of rot[pos][d]. 262144 entries.
// ---------------------------------------------------------------------------
__global__ __launch_bounds__(256) void csin_kernel(const float* __restrict__ rot,
                                                   float2* __restrict__ csin) {
    const int i = blockIdx.x * 256 + threadIdx.x;
    float s, c;
    sincosf(rot[i], &s, &c);
    csin[i] = make_float2(c, s);
}

// ---------------------------------------------------------------------------
// RoPE (table-based) in-place on the K half of qk [8192][1024] only
// (Q rope is fused into attn's register Q load). One wave per (b,pos).
// ---------------------------------------------------------------------------
__global__ __launch_bounds__(256) void rope_k_kernel(__bf16* __restrict__ qk,
                                                     const float2* __restrict__ csin) {
    const int row = blockIdx.x * 4 + (threadIdx.x >> 6);   // b*4096+pos
    const int lane = threadIdx.x & 63;
    const int h = lane >> 3, dl = (lane & 7) * 4;
    const int pos = row & 4095;
    const float4 csA = *reinterpret_cast<const float4*>(&csin[pos * 64 + dl]);
    const float4 csB = *reinterpret_cast<const float4*>(&csin[pos * 64 + dl + 2]);
    const float4 csC = *reinterpret_cast<const float4*>(&csin[pos * 64 + dl + 32]);
    const float4 csD = *reinterpret_cast<const float4*>(&csin[pos * 64 + dl + 34]);
    const float c0[4] = {csA.x, csA.z, csB.x, csB.z};
    const float s0[4] = {csA.y, csA.w, csB.y, csB.w};
    const float c1[4] = {csC.x, csC.z, csD.x, csD.z};
    const float s1[4] = {csC.y, csC.w, csD.y, csD.w};
    __bf16* pp = qk + (size_t)row * 1024 + 512 + h * 64 + dl;
    union { uint2 u; __bf16 hh[4]; } va, vb, oa, ob;
    va.u = *reinterpret_cast<const uint2*>(pp);
    vb.u = *reinterpret_cast<const uint2*>(pp + 32);
#pragma unroll
    for (int j = 0; j < 4; ++j) {
        const float a = (float)va.hh[j], b2 = (float)vb.hh[j];
        oa.hh[j] = (__bf16)(a * c0[j] - b2 * s0[j]);
        ob.hh[j] = (__bf16)(b2 * c1[j] + a * s1[j]);
    }
    *reinterpret_cast<uint2*>(pp)      = oa.u;
    *reinterpret_cast<uint2*>(pp + 32) = ob.u;
}

// ---------------------------------------------------------------------------
// GEMM: C(MxN) = A(MxK) @ Bt(NxK)^T, bf16 in, fp32 accum.
// Ring-3 LDS, counted vmcnt(4) barriers, bijective XCD swizzle.
// MODE 0: float output, ld = N. MODE 1 (QKV): cols <1024 -> qk buf
// [8192][1024] bf16 (raw q/k); v -> vt[1024][4096] transposed + kappa.
// ---------------------------------------------------------------------------
template <typename OutT, int MODE>
__global__ __launch_bounds__(256) void gemm_bt(const __bf16* __restrict__ A,
                                               const __bf16* __restrict__ Bt,
                                               OutT* __restrict__ C,
                                               __bf16* __restrict__ vt,
                                               int M, int N, int K) {
    __shared__ __align__(16) __bf16 As[3][128 * 32];
    __shared__ __align__(16) __bf16 Bs[3][128 * 32];
    const int nbn = N >> 7;
    const int xcd = blockIdx.x & 7;
    const int idx = blockIdx.x >> 3;
    const int bm = xcd * 8 + idx / nbn;
    const int bn = idx % nbn;
    const int tid = threadIdx.x;
    const int w = tid >> 6, l = tid & 63, lg = l >> 4, lr = l & 15;
    const int wr = w >> 1, wc = w & 1;
    const __bf16* Ab = A + (size_t)(bm * 128) * K;
    const __bf16* Bb = Bt + (size_t)(bn * 128) * K;
    const int srow = tid >> 2, scol = (tid & 3) * 8;
    const __bf16* Asrc = Ab + (size_t)srow * K + scol;
    const __bf16* Bsrc = Bb + (size_t)srow * K + scol;

    auto stage = [&](int k2) {
        const int nx = k2 % 3;
        const int off = k2 * 32;
        gload16(&As[nx][tid * 8],        Asrc + off);
        gload16(&As[nx][2048 + tid * 8], Asrc + (size_t)64 * K + off);
        gload16(&Bs[nx][tid * 8],        Bsrc + off);
        gload16(&Bs[nx][2048 + tid * 8], Bsrc + (size_t)64 * K + off);
    };

    const int NS = K >> 5;
    f32x4 acc[4][4] = {};
    stage(0);
    stage(1);
    wait_barrier4();
    for (int k = 0; k < NS; ++k) {
        const bool more = (k + 2 < NS);
        if (more) stage(k + 2);
        const __bf16* Ac = &As[k % 3][0];
        const __bf16* Bc = &Bs[k % 3][0];
        bf16x8 af[4], bfr[4];
#pragma unroll
        for (int m = 0; m < 4; ++m)
            af[m] = *reinterpret_cast<const bf16x8*>(Ac + (wr * 64 + m * 16 + lr) * 32 + lg * 8);
#pragma unroll
        for (int nn = 0; nn < 4; ++nn)
            bfr[nn] = *reinterpret_cast<const bf16x8*>(Bc + (wc * 64 + nn * 16 + lr) * 32 + lg * 8);
#pragma unroll
        for (int m = 0; m < 4; ++m)
#pragma unroll
            for (int nn = 0; nn < 4; ++nn)
                acc[m][nn] = __builtin_amdgcn_mfma_f32_16x16x32_bf16(af[m], bfr[nn],
                                                                     acc[m][nn], 0, 0, 0);
        if (more) wait_barrier4();
        else      wait_barrier0();
    }
    if constexpr (MODE == 1) {
        const int cb = bn * 128 + wc * 64;
        if (cb < 1024) {                          // q,k -> qk buf (ld 1024)
#pragma unroll
            for (int m = 0; m < 4; ++m) {
                const int rg = bm * 128 + wr * 64 + m * 16 + 4 * lg;
#pragma unroll
                for (int nn = 0; nn < 4; ++nn) {
                    const int cg = cb + nn * 16 + lr;
#pragma unroll
                    for (int r = 0; r < 4; ++r)
                        C[(size_t)(rg + r) * 1024 + cg] = (OutT)acc[m][nn][r];
                }
            }
        } else {                                  // v -> vt transposed + kappa
#pragma unroll
            for (int m = 0; m < 4; ++m) {
                const int rg = bm * 128 + wr * 64 + m * 16 + 4 * lg;
                const int bidx = rg >> 12, pos0 = rg & 4095;
                const int a0 = pos0 & 63;
                const int cp = 32 * (a0 >> 5) + 8 * ((a0 >> 2) & 3) + 4 * ((a0 >> 4) & 1);
                const int nbase = (pos0 & ~63) + cp;
#pragma unroll
                for (int nn = 0; nn < 4; ++nn) {
                    const int col = cb + nn * 16 + lr - 1024;
                    const int hh = col >> 6, dd = col & 63;
                    union { __bf16 h4[4]; uint2 u; } pk2;
#pragma unroll
                    for (int r = 0; r < 4; ++r) pk2.h4[r] = (__bf16)acc[m][nn][r];
                    *reinterpret_cast<uint2*>(&vt[((size_t)(bidx * 8 + hh) * 64 + dd) * 4096 + nbase]) = pk2.u;
                }
            }
        }
        return;
    }
#pragma unroll
    for (int m = 0; m < 4; ++m) {
        const int rg = bm * 128 + wr * 64 + m * 16 + 4 * lg;
#pragma unroll
        for (int nn = 0; nn < 4; ++nn) {
            const int cg = bn * 128 + wc * 64 + nn * 16 + lr;
#pragma unroll
            for (int r = 0; r < 4; ++r)
                C[(size_t)(rg + r) * N + cg] = (OutT)acc[m][nn][r];
        }
    }
}

// ---------------------------------------------------------------------------
// Causal flash attention v16: 32 q-rows/wave (halves LDS-read per row, the
// R14 bottleneck) + R6-style IN-BLOCK complementary pairing for balance:
// 256 blocks x 256 thr (4 waves x 32 rows, QBLK=128); block runs segments
// qt=p then qt=31-p -> exactly 66 tile-units per block, 1 block/CU,
// independent of dispatch order (R15's failure was scheduler-dependent
// pairing: all blocks resident at t=0 -> no rebalancing -> 2x imbalance).
// Ring-3 K/V, zero-VALU staging, fused Q-rope, ones-Lacc, unroll x6.
// ---------------------------------------------------------------------------
__global__ __launch_bounds__(256) void attn_kernel(const __bf16* __restrict__ qkp,
                                                   const __bf16* __restrict__ vt,
                                                   const float2* __restrict__ csin,
                                                   __bf16* __restrict__ attn_out) {
    const int bid = blockIdx.x;                      // 256 blocks
    const int bh = 2 * (bid & 7) + ((bid >> 3) & 1); // 2 heads per XCD
    const int p  = bid >> 4;                         // pair id 0..15
    const int b = bh >> 3, h = bh & 7;
    const int tid = threadIdx.x;
    const int w = tid >> 6, l = tid & 63, lg = l >> 4, lr = l & 15;

    __shared__ __align__(16) __bf16 Ks[3][64 * 64];
    __shared__ __align__(16) __bf16 Vs[3][64 * 64];

    const __bf16* qbase = qkp + (size_t)b * 4096 * 1024 + h * 64;
    const __bf16* kbase = qbase + 512;
    const __bf16* vtb   = vt + (size_t)(b * 8 + h) * 64 * 4096;

    const int sr = tid >> 3;
    const int sc = ((tid & 7) ^ (sr & 7)) * 8;
    const __bf16* ksrc0 = kbase + (size_t)sr * 1024 + sc;
    const __bf16* vsrc0 = vtb + (size_t)sr * 4096 + sc;

    const int xel = (lr & 7) * 8;                    // read-side swizzle

    bf16x8 ones;
#pragma unroll
    for (int i = 0; i < 8; ++i) ones[i] = (__bf16)1.0f;

    for (int seg = 0; seg < 2; ++seg) {
        const int qt = seg ? (31 - p) : p;
        const int wq0 = qt * 128 + 32 * w;           // wave owns 32 rows
        const int nkt = 2 * qt + 2;
        const __bf16* kp = ksrc0;
        const __bf16* vp = vsrc0;

        auto stage2 = [&](__bf16* kdst, __bf16* vdst) {
            gload16(kdst + tid * 8,         kp);
            gload16(kdst + (tid + 256) * 8, kp + 32 * 1024);
            gload16(vdst + tid * 8,         vp);
            gload16(vdst + (tid + 256) * 8, vp + 32 * 4096);
            kp += 64 * 1024;
            vp += 64;
        };

        // prologue part 1: stage tiles 0,1 (fly under Q-rope VALU)
        stage2(Ks[0], Vs[0]);
        stage2(Ks[1], Vs[1]);

        // Q load + fused rope (+ 1/sqrt(d) * log2e) for both 16-row sub-tiles
        bf16x8 Qf[2][2];
#pragma unroll
        for (int nt = 0; nt < 2; ++nt) {
            const int qrow = wq0 + 16 * nt + lr;
            const __bf16* qp = qbase + (size_t)qrow * 1024 + 8 * lg;
            const bf16x8 rq0 = *reinterpret_cast<const bf16x8*>(qp);
            const bf16x8 rq1 = *reinterpret_cast<const bf16x8*>(qp + 32);
            const float2* csp = csin + (size_t)qrow * 64 + 8 * lg;
            const float qs = 0.125f * LOG2E;
#pragma unroll
            for (int i = 0; i < 8; ++i) {
                const float2 ca = csp[i];
                const float2 cb = csp[i + 32];
                const float a = (float)rq0[i], b2 = (float)rq1[i];
                Qf[nt][0][i] = (__bf16)((a * ca.x - b2 * ca.y) * qs);
                Qf[nt][1][i] = (__bf16)((b2 * cb.x + a * cb.y) * qs);
            }
        }

        f32x4 O[2][4] = {};
        f32x4 Lacc[2] = {};
        float m_[2] = {-1e30f, -1e30f};

        auto qk_step = [&](f32x4 (&S)[2][4], const __bf16* kb) {
            __builtin_amdgcn_s_setprio(1);
#pragma unroll
            for (int jt = 0; jt < 4; ++jt) {
                const __bf16* kr = kb + (16 * jt + lr) * 64;
                const bf16x8 Kf0 = *reinterpret_cast<const bf16x8*>(kr + ((8 * lg) ^ xel));
                const bf16x8 Kf1 = *reinterpret_cast<const bf16x8*>(kr + ((32 + 8 * lg) ^ xel));
#pragma unroll
                for (int nt = 0; nt < 2; ++nt) {
                    f32x4 z = {};
                    z = __builtin_amdgcn_mfma_f32_16x16x32_bf16(Kf0, Qf[nt][0], z, 0, 0, 0);
                    S[nt][jt] = __builtin_amdgcn_mfma_f32_16x16x32_bf16(Kf1, Qf[nt][1], z, 0, 0, 0);
                }
            }
            __builtin_amdgcn_s_setprio(0);
        };
        auto smpv = [&](f32x4 (&SC)[2][4], const __bf16* vb, int kt0, bool tail) {
            bool act[2] = {true, true};
            if (tail) {
#pragma unroll
                for (int nt = 0; nt < 2; ++nt) {
                    act[nt] = (64 * kt0 <= wq0 + 16 * nt + 15);
                    if (act[nt] && 64 * kt0 + 63 > wq0 + 16 * nt) {
                        const int thr = wq0 + 16 * nt + lr - 64 * kt0;
#pragma unroll
                        for (int jt = 0; jt < 4; ++jt)
#pragma unroll
                            for (int r = 0; r < 4; ++r)
                                if (16 * jt + 4 * lg + r > thr) SC[nt][jt][r] = -1e30f;
                    }
                }
            }
#pragma unroll
            for (int nt = 0; nt < 2; ++nt) {
                if (!act[nt]) continue;
                float mx = -1e30f;
#pragma unroll
                for (int jt = 0; jt < 4; ++jt)
                    mx = fmaxf(mx, fmaxf(fmaxf(SC[nt][jt][0], SC[nt][jt][1]),
                                         fmaxf(SC[nt][jt][2], SC[nt][jt][3])));
                if (__any(mx > m_[nt] + 8.0f)) {
                    mx = fmaxf(mx, __shfl_xor(mx, 16));
                    mx = fmaxf(mx, __shfl_xor(mx, 32));
                    const float mn = fmaxf(m_[nt], mx);
                    const float alpha = __builtin_amdgcn_exp2f(m_[nt] - mn);
                    m_[nt] = mn;
                    Lacc[nt] *= alpha;
#pragma unroll
                    for (int dt = 0; dt < 4; ++dt) O[nt][dt] *= alpha;
                }
#pragma unroll
                for (int jt = 0; jt < 4; ++jt)
#pragma unroll
                    for (int r = 0; r < 4; ++r)
                        SC[nt][jt][r] = __builtin_amdgcn_exp2f(SC[nt][jt][r] - m_[nt]);
            }
            bf16x8 Pf[2][2];
#pragma unroll
            for (int nt = 0; nt < 2; ++nt)
                if (act[nt])
#pragma unroll
                    for (int s = 0; s < 2; ++s)
#pragma unroll
                        for (int i = 0; i < 8; ++i)
                            Pf[nt][s][i] = (__bf16)SC[nt][2 * s + (i >> 2)][i & 3];
            __builtin_amdgcn_s_setprio(1);
#pragma unroll
            for (int nt = 0; nt < 2; ++nt)
                if (act[nt])
#pragma unroll
                    for (int s = 0; s < 2; ++s)
                        Lacc[nt] = __builtin_amdgcn_mfma_f32_16x16x32_bf16(ones, Pf[nt][s], Lacc[nt], 0, 0, 0);
#pragma unroll
            for (int s = 0; s < 2; ++s)
#pragma unroll
                for (int dt = 0; dt < 4; ++dt) {
                    const bf16x8 Vf = *reinterpret_cast<const bf16x8*>(
                        vb + (16 * dt + lr) * 64 + ((32 * s + 8 * lg) ^ xel));
                    if (act[0]) O[0][dt] = __builtin_amdgcn_mfma_f32_16x16x32_bf16(Vf, Pf[0][s], O[0][dt], 0, 0, 0);
                    if (act[1]) O[1][dt] = __builtin_amdgcn_mfma_f32_16x16x32_bf16(Vf, Pf[1][s], O[1][dt], 0, 0, 0);
                }
            __builtin_amdgcn_s_setprio(0);
        };

        f32x4 S0[2][4], S1[2][4];
        int t = 0;

        // prologue part 2: tiles 0,1 landed; S0 = QK(0)
        __syncthreads();
        qk_step(S0, Ks[0]);

        // main loop: 6 statically-indexed bodies, all pre-diagonal
        for (; t + 8 <= nkt; t += 6) {
            stage2(Ks[2], Vs[2]); qk_step(S1, Ks[1]); smpv(S0, Vs[0], t,     false); __syncthreads();
            stage2(Ks[0], Vs[0]); qk_step(S0, Ks[2]); smpv(S1, Vs[1], t + 1, false); __syncthreads();
            stage2(Ks[1], Vs[1]); qk_step(S1, Ks[0]); smpv(S0, Vs[2], t + 2, false); __syncthreads();
            stage2(Ks[2], Vs[2]); qk_step(S0, Ks[1]); smpv(S1, Vs[0], t + 3, false); __syncthreads();
            stage2(Ks[0], Vs[0]); qk_step(S1, Ks[2]); smpv(S0, Vs[1], t + 4, false); __syncthreads();
            stage2(Ks[1], Vs[1]); qk_step(S0, Ks[0]); smpv(S1, Vs[2], t + 5, false); __syncthreads();
        }

        // tail: <=7 tiles, dynamic ring indices, per-nt skip/mask near diag
        {
            f32x4 Sp[2][4];
#pragma unroll
            for (int nt = 0; nt < 2; ++nt)
#pragma unroll
                for (int jt = 0; jt < 4; ++jt) Sp[nt][jt] = S0[nt][jt];
            for (; t < nkt; ++t) {
                if (t + 2 < nkt) stage2(Ks[(t + 2) % 3], Vs[(t + 2) % 3]);
                f32x4 Sn[2][4];
                if (t + 1 < nkt) qk_step(Sn, Ks[(t + 1) % 3]);
                smpv(Sp, Vs[t % 3], t, true);
                __syncthreads();
#pragma unroll
                for (int nt = 0; nt < 2; ++nt)
#pragma unroll
                    for (int jt = 0; jt < 4; ++jt) Sp[nt][jt] = Sn[nt][jt];
            }
        }

        // epilogue: Lacc[nt][0] is already the full row-sum (MFMA reduced)
#pragma unroll
        for (int nt = 0; nt < 2; ++nt) {
            const float inv = 1.0f / Lacc[nt][0];
            __bf16* op = attn_out + ((size_t)b * 4096 + wq0 + 16 * nt + lr) * 512 + h * 64;
#pragma unroll
            for (int dt = 0; dt < 4; ++dt) {
                union { __bf16 h4[4]; uint2 u; } ow;
#pragma unroll
                for (int r = 0; r < 4; ++r) ow.h4[r] = (__bf16)(O[nt][dt][r] * inv);
                *reinterpret_cast<uint2*>(op + 16 * dt + 4 * lg) = ow.u;
            }
        }
    }
}

// ---------------------------------------------------------------------------
extern "C" void kernel_launch(void* const* d_in, const int* in_sizes, int n_in,
                              void* d_out, int out_size, void* d_ws, size_t ws_size,
                              hipStream_t stream) {
    (void)in_sizes; (void)n_in; (void)out_size; (void)ws_size;
    const float* x    = (const float*)d_in[0];
    const float* rot  = (const float*)d_in[1];
    const float* rmsw = (const float*)d_in[2];
    const float* wqkv = (const float*)d_in[3];
    const float* wout = (const float*)d_in[4];
    float* out = (float*)d_out;

    char* ws = (char*)d_ws;
    __bf16* xn    = (__bf16*)ws;                       // 16,777,216 B
    __bf16* wqkvt = (__bf16*)(ws + 16777216);          //  3,145,728 B
    __bf16* woutt = (__bf16*)(ws + 16777216 + 3145728);//  1,048,576 B
    __bf16* aout  = (__bf16*)(ws + 16777216 + 3145728 + 1048576); // 8,388,608 B
    // d_out during pipeline: qk [0,16.78M), csin [16.78M,18.87M),
    // vt [18.87M,27.26M) — all dead before the final GEMM overwrites d_out.
    __bf16* qk   = (__bf16*)d_out;
    float2* csin = (float2*)((char*)d_out + 16777216);
    __bf16* vt   = (__bf16*)((char*)d_out + 18874368);

    rmsnorm_kernel<<<8192, 256, 0, stream>>>(x, rmsw, xn);
    transpose_cast_kernel<<<dim3(48, 32), dim3(32, 8), 0, stream>>>(wqkv, wqkvt, 1024, 1536);
    transpose_cast_kernel<<<dim3(32, 16), dim3(32, 8), 0, stream>>>(wout, woutt, 512, 1024);
    csin_kernel<<<1024, 256, 0, stream>>>(rot, csin);
    gemm_bt<__bf16, 1><<<768, 256, 0, stream>>>(xn, wqkvt, qk, vt, 8192, 1536, 1024);
    rope_k_kernel<<<2048, 256, 0, stream>>>(qk, csin);
    attn_kernel<<<256, 256, 0, stream>>>(qk, vt, csin, aout);
    gemm_bt<float, 0><<<512, 256, 0, stream>>>(aout, woutt, out, nullptr, 8192, 1024, 512);
}

// Round 17
// 137.045 us; speedup vs baseline: 1.4408x; 1.1752x over previous
//
#include <hip/hip_runtime.h>
#include <hip/hip_bf16.h>
#include <cstdint>

using bf16x8 = __attribute__((ext_vector_type(8))) __bf16;
using f32x4  = __attribute__((ext_vector_type(4))) float;

#define LOG2E 1.4426950408889634f

__device__ inline void gload16(__bf16* lds, const __bf16* g) {
    __builtin_amdgcn_global_load_lds((const __attribute__((address_space(1))) void*)g,
                                     (__attribute__((address_space(3))) void*)lds, 16, 0, 0);
}
__device__ inline void wait_barrier4() {
    asm volatile("s_waitcnt vmcnt(4)" ::: "memory");
    __builtin_amdgcn_s_barrier();
}
__device__ inline void wait_barrier0() {
    asm volatile("s_waitcnt vmcnt(0)" ::: "memory");
    __builtin_amdgcn_s_barrier();
}
__device__ inline void bar_mem() {
    asm volatile("s_barrier" ::: "memory");
}
__device__ inline void vm_bar(int n) {   // n is compile-time 0 or 4 at call sites
    if (n == 0) asm volatile("s_waitcnt vmcnt(0)\ns_barrier" ::: "memory");
    else        asm volatile("s_waitcnt vmcnt(4)\ns_barrier" ::: "memory");
}

// ---------------------------------------------------------------------------
// RMSNorm: one block (256 threads) per row of 1024 fp32 -> bf16
// ---------------------------------------------------------------------------
__global__ __launch_bounds__(256) void rmsnorm_kernel(const float* __restrict__ x,
                                                      const float* __restrict__ w,
                                                      __bf16* __restrict__ xn) {
    const int row = blockIdx.x;
    const float4 v = reinterpret_cast<const float4*>(x + (size_t)row * 1024)[threadIdx.x];
    float ss = v.x * v.x + v.y * v.y + v.z * v.z + v.w * v.w;
#pragma unroll
    for (int i = 1; i < 64; i <<= 1) ss += __shfl_xor(ss, i);
    __shared__ float part[4];
    if ((threadIdx.x & 63) == 0) part[threadIdx.x >> 6] = ss;
    __syncthreads();
    const float total = part[0] + part[1] + part[2] + part[3];
    const float scale = rsqrtf(total * (1.0f / 1024.0f) + 1.1920929e-07f);
    const float4 wv = reinterpret_cast<const float4*>(w)[threadIdx.x];
    union { __bf16 h[4]; uint2 u; } pk;
    pk.h[0] = (__bf16)(v.x * scale * wv.x);
    pk.h[1] = (__bf16)(v.y * scale * wv.y);
    pk.h[2] = (__bf16)(v.z * scale * wv.z);
    pk.h[3] = (__bf16)(v.w * scale * wv.w);
    reinterpret_cast<uint2*>(xn + (size_t)row * 1024)[threadIdx.x] = pk.u;
}

// ---------------------------------------------------------------------------
// Transpose + cast: in (K x N) fp32 row-major -> out (N x K) bf16 row-major
// ---------------------------------------------------------------------------
__global__ void transpose_cast_kernel(const float* __restrict__ in,
                                      __bf16* __restrict__ out, int K, int N) {
    __shared__ float tile[32][33];
    const int n0 = blockIdx.x * 32, k0 = blockIdx.y * 32;
#pragma unroll
    for (int r = threadIdx.y; r < 32; r += 8)
        tile[r][threadIdx.x] = in[(size_t)(k0 + r) * N + n0 + threadIdx.x];
    __syncthreads();
#pragma unroll
    for (int r = threadIdx.y; r < 32; r += 8)
        out[(size_t)(n0 + r) * K + k0 + threadIdx.x] = (__bf16)tile[threadIdx.x][r];
}

// ---------------------------------------------------------------------------
// cos/sin table: csin[pos*64+d] = (cos, sin) of rot[pos][d]. 262144 entries.
// ---------------------------------------------------------------------------
__global__ __launch_bounds__(256) void csin_kernel(const float* __restrict__ rot,
                                                   float2* __restrict__ csin) {
    const int i = blockIdx.x * 256 + threadIdx.x;
    float s, c;
    sincosf(rot[i], &s, &c);
    csin[i] = make_float2(c, s);
}

// ---------------------------------------------------------------------------
// RoPE (table-based) in-place on the K half of qk [8192][1024] only
// (Q rope is fused into attn's register Q load). One wave per (b,pos).
// ---------------------------------------------------------------------------
__global__ __launch_bounds__(256) void rope_k_kernel(__bf16* __restrict__ qk,
                                                     const float2* __restrict__ csin) {
    const int row = blockIdx.x * 4 + (threadIdx.x >> 6);   // b*4096+pos
    const int lane = threadIdx.x & 63;
    const int h = lane >> 3, dl = (lane & 7) * 4;
    const int pos = row & 4095;
    const float4 csA = *reinterpret_cast<const float4*>(&csin[pos * 64 + dl]);
    const float4 csB = *reinterpret_cast<const float4*>(&csin[pos * 64 + dl + 2]);
    const float4 csC = *reinterpret_cast<const float4*>(&csin[pos * 64 + dl + 32]);
    const float4 csD = *reinterpret_cast<const float4*>(&csin[pos * 64 + dl + 34]);
    const float c0[4] = {csA.x, csA.z, csB.x, csB.z};
    const float s0[4] = {csA.y, csA.w, csB.y, csB.w};
    const float c1[4] = {csC.x, csC.z, csD.x, csD.z};
    const float s1[4] = {csC.y, csC.w, csD.y, csD.w};
    __bf16* pp = qk + (size_t)row * 1024 + 512 + h * 64 + dl;
    union { uint2 u; __bf16 hh[4]; } va, vb, oa, ob;
    va.u = *reinterpret_cast<const uint2*>(pp);
    vb.u = *reinterpret_cast<const uint2*>(pp + 32);
#pragma unroll
    for (int j = 0; j < 4; ++j) {
        const float a = (float)va.hh[j], b2 = (float)vb.hh[j];
        oa.hh[j] = (__bf16)(a * c0[j] - b2 * s0[j]);
        ob.hh[j] = (__bf16)(b2 * c1[j] + a * s1[j]);
    }
    *reinterpret_cast<uint2*>(pp)      = oa.u;
    *reinterpret_cast<uint2*>(pp + 32) = ob.u;
}

// ---------------------------------------------------------------------------
// QKV GEMM, 256x256 8-phase template (T2+T3+T4+T5). C = A(8192x1024) @
// Bt(1536x1024)^T. 512 thr = 8 waves (2Mx4N); wave output 128x64.
// BK=64 split in two kk-halves; LDS [2buf][2kk][256x32] per matrix (128KB),
// XOR swizzle c8l^=(row>>1)&3 (2-way free on ds_read_b128; linear
// global_load_lds dest + pre-swizzled source). 8 phases/iter covering 2
// K-tiles; counted vmcnt(4) ONLY at phases 4/8 (loads stay in flight across
// barriers); staging of each kk-half is issued >=1 phase after its region's
// last reader (verified phase-by-phase). Epilogue: cols<1024 -> qk buf,
// else v -> vt[1024][4096] transposed + kappa-permuted.
// ---------------------------------------------------------------------------
__global__ __launch_bounds__(512) void gemm8_qkv(const __bf16* __restrict__ A,
                                                 const __bf16* __restrict__ Bt,
                                                 __bf16* __restrict__ qk,
                                                 __bf16* __restrict__ vt) {
    __shared__ __align__(16) __bf16 AL[2 * 2 * 8192];   // [buf][kk][256*32]
    __shared__ __align__(16) __bf16 BL[2 * 2 * 8192];
    const int xcd = blockIdx.x & 7;
    const int idx = blockIdx.x >> 3;         // 0..23
    const int bm = xcd * 4 + idx / 6;        // A panels XCD-local
    const int bn = idx % 6;
    const int tid = threadIdx.x;
    const int wid = tid >> 6, l = tid & 63, lg = l >> 4, lr = l & 15;
    const int wr = wid >> 2, wc = wid & 3;
    const int swzr = (lr >> 1) & 3;          // read-side swizzle (lane const)

    // staging: thread covers granules d=tid and d=tid+512 of each 256x32 chunk
    const int srow0 = tid >> 2;
    const int sswz = (tid & 3) ^ ((srow0 >> 1) & 3);
    const __bf16* Asrc0 = A + (size_t)(bm * 256 + srow0) * 1024 + sswz * 8;
    const __bf16* Asrc1 = Asrc0 + (size_t)128 * 1024;
    const __bf16* Bsrc0 = Bt + (size_t)(bn * 256 + srow0) * 1024 + sswz * 8;
    const __bf16* Bsrc1 = Bsrc0 + (size_t)128 * 1024;

    auto stageA = [&](int buf, int kk, int t) {
        __bf16* base = AL + buf * 16384 + kk * 8192;
        gload16(base + tid * 8,        Asrc0 + t * 64 + kk * 32);
        gload16(base + 4096 + tid * 8, Asrc1 + t * 64 + kk * 32);
    };
    auto stageB = [&](int buf, int kk, int t) {
        __bf16* base = BL + buf * 16384 + kk * 8192;
        gload16(base + tid * 8,        Bsrc0 + t * 64 + kk * 32);
        gload16(base + 4096 + tid * 8, Bsrc1 + t * 64 + kk * 32);
    };

    f32x4 acc[8][4] = {};
    bf16x8 bcache[4];

    auto loadA = [&](bf16x8 (&af)[4], int buf, int kk, int rh) {
        const __bf16* base = AL + buf * 16384 + kk * 8192;
#pragma unroll
        for (int mm = 0; mm < 4; ++mm) {
            const int row = wr * 128 + (4 * rh + mm) * 16 + lr;
            af[mm] = *reinterpret_cast<const bf16x8*>(base + row * 32 + ((lg ^ swzr) << 3));
        }
    };
    auto loadB = [&](int buf, int kk) {
        const __bf16* base = BL + buf * 16384 + kk * 8192;
#pragma unroll
        for (int nn = 0; nn < 4; ++nn) {
            const int row = wc * 64 + nn * 16 + lr;
            bcache[nn] = *reinterpret_cast<const bf16x8*>(base + row * 32 + ((lg ^ swzr) << 3));
        }
    };
    auto mfma16 = [&](bf16x8 (&af)[4], int rh) {
        __builtin_amdgcn_s_setprio(1);
#pragma unroll
        for (int mm = 0; mm < 4; ++mm)
#pragma unroll
            for (int nn = 0; nn < 4; ++nn)
                acc[4 * rh + mm][nn] = __builtin_amdgcn_mfma_f32_16x16x32_bf16(
                    af[mm], bcache[nn], acc[4 * rh + mm][nn], 0, 0, 0);
        __builtin_amdgcn_s_setprio(0);
    };

    // prologue: tile 0 full (buf0) + tile 1 kk0 (buf1); X landed, Y-kk0 flying
    stageA(0, 0, 0); stageB(0, 0, 0);
    stageA(0, 1, 0); stageB(0, 1, 0);
    stageA(1, 0, 1); stageB(1, 0, 1);
    vm_bar(4);

    const int NITER = 8;                     // 16 K-tiles of 64
    for (int I = 0; I < NITER; ++I) {
        const bool more = (I < NITER - 1);
        bf16x8 af[4];
        // ph1: X kk0 rh0 | stage Y(tile 2I+1) kk1
        loadA(af, 0, 0, 0); loadB(0, 0);
        stageA(1, 1, 2 * I + 1); stageB(1, 1, 2 * I + 1);
        bar_mem(); mfma16(af, 0); bar_mem();
        // ph2: X kk0 rh1
        loadA(af, 0, 0, 1);
        bar_mem(); mfma16(af, 1); bar_mem();
        // ph3: X kk1 rh0 | stage Xnext kk0 A
        loadA(af, 0, 1, 0); loadB(0, 1);
        if (more) stageA(0, 0, 2 * I + 2);
        bar_mem(); mfma16(af, 0); bar_mem();
        // ph4: X kk1 rh1 | stage Xnext kk0 B | vmcnt
        loadA(af, 0, 1, 1);
        if (more) { stageB(0, 0, 2 * I + 2); vm_bar(4); }
        else      { vm_bar(0); }
        mfma16(af, 1); bar_mem();
        // ph5: Y kk0 rh0 | stage Xnext kk1 A+B
        loadA(af, 1, 0, 0); loadB(1, 0);
        if (more) { stageA(0, 1, 2 * I + 2); stageB(0, 1, 2 * I + 2); }
        bar_mem(); mfma16(af, 0); bar_mem();
        // ph6: Y kk0 rh1
        loadA(af, 1, 0, 1);
        bar_mem(); mfma16(af, 1); bar_mem();
        // ph7: Y kk1 rh0 | stage Ynext kk0 A
        loadA(af, 1, 1, 0); loadB(1, 1);
        if (more) stageA(1, 0, 2 * I + 3);
        bar_mem(); mfma16(af, 0); bar_mem();
        // ph8: Y kk1 rh1 | stage Ynext kk0 B | vmcnt
        loadA(af, 1, 1, 1);
        if (more) { stageB(1, 0, 2 * I + 3); vm_bar(4); }
        else      { vm_bar(0); }
        mfma16(af, 1); bar_mem();
    }

    // epilogue
    const int cb = bn * 256 + wc * 64;
    if (cb < 1024) {                          // q,k -> qk buf (ld 1024)
#pragma unroll
        for (int m = 0; m < 8; ++m) {
            const int rg = bm * 256 + wr * 128 + m * 16 + 4 * lg;
#pragma unroll
            for (int nn = 0; nn < 4; ++nn) {
                const int cg = cb + nn * 16 + lr;
#pragma unroll
                for (int r = 0; r < 4; ++r)
                    qk[(size_t)(rg + r) * 1024 + cg] = (__bf16)acc[m][nn][r];
            }
        }
    } else {                                  // v -> vt transposed + kappa
#pragma unroll
        for (int m = 0; m < 8; ++m) {
            const int rg = bm * 256 + wr * 128 + m * 16 + 4 * lg;
            const int bidx = rg >> 12, pos0 = rg & 4095;
            const int a0 = pos0 & 63;
            const int cp = 32 * (a0 >> 5) + 8 * ((a0 >> 2) & 3) + 4 * ((a0 >> 4) & 1);
            const int nbase = (pos0 & ~63) + cp;
#pragma unroll
            for (int nn = 0; nn < 4; ++nn) {
                const int col = cb + nn * 16 + lr - 1024;
                const int hh = col >> 6, dd = col & 63;
                union { __bf16 h4[4]; uint2 u; } pk2;
#pragma unroll
                for (int r = 0; r < 4; ++r) pk2.h4[r] = (__bf16)acc[m][nn][r];
                *reinterpret_cast<uint2*>(&vt[((size_t)(bidx * 8 + hh) * 64 + dd) * 4096 + nbase]) = pk2.u;
            }
        }
    }
}

// ---------------------------------------------------------------------------
// Out-proj GEMM: C(MxN fp32) = A(MxK) @ Bt(NxK)^T. 128^2 tile, ring-3,
// counted vmcnt(4) barriers, bijective XCD swizzle (R14 version).
// ---------------------------------------------------------------------------
__global__ __launch_bounds__(256) void gemm_out(const __bf16* __restrict__ A,
                                                const __bf16* __restrict__ Bt,
                                                float* __restrict__ C,
                                                int M, int N, int K) {
    __shared__ __align__(16) __bf16 As[3][128 * 32];
    __shared__ __align__(16) __bf16 Bs[3][128 * 32];
    const int nbn = N >> 7;
    const int xcd = blockIdx.x & 7;
    const int idx = blockIdx.x >> 3;
    const int bm = xcd * 8 + idx / nbn;
    const int bn = idx % nbn;
    const int tid = threadIdx.x;
    const int w = tid >> 6, l = tid & 63, lg = l >> 4, lr = l & 15;
    const int wr = w >> 1, wc = w & 1;
    const __bf16* Ab = A + (size_t)(bm * 128) * K;
    const __bf16* Bb = Bt + (size_t)(bn * 128) * K;
    const int srow = tid >> 2, scol = (tid & 3) * 8;
    const __bf16* Asrc = Ab + (size_t)srow * K + scol;
    const __bf16* Bsrc = Bb + (size_t)srow * K + scol;

    auto stage = [&](int k2) {
        const int nx = k2 % 3;
        const int off = k2 * 32;
        gload16(&As[nx][tid * 8],        Asrc + off);
        gload16(&As[nx][2048 + tid * 8], Asrc + (size_t)64 * K + off);
        gload16(&Bs[nx][tid * 8],        Bsrc + off);
        gload16(&Bs[nx][2048 + tid * 8], Bsrc + (size_t)64 * K + off);
    };

    const int NS = K >> 5;
    f32x4 acc[4][4] = {};
    stage(0);
    stage(1);
    wait_barrier4();
    for (int k = 0; k < NS; ++k) {
        const bool more = (k + 2 < NS);
        if (more) stage(k + 2);
        const __bf16* Ac = &As[k % 3][0];
        const __bf16* Bc = &Bs[k % 3][0];
        bf16x8 af[4], bfr[4];
#pragma unroll
        for (int m = 0; m < 4; ++m)
            af[m] = *reinterpret_cast<const bf16x8*>(Ac + (wr * 64 + m * 16 + lr) * 32 + lg * 8);
#pragma unroll
        for (int nn = 0; nn < 4; ++nn)
            bfr[nn] = *reinterpret_cast<const bf16x8*>(Bc + (wc * 64 + nn * 16 + lr) * 32 + lg * 8);
#pragma unroll
        for (int m = 0; m < 4; ++m)
#pragma unroll
            for (int nn = 0; nn < 4; ++nn)
                acc[m][nn] = __builtin_amdgcn_mfma_f32_16x16x32_bf16(af[m], bfr[nn],
                                                                     acc[m][nn], 0, 0, 0);
        if (more) wait_barrier4();
        else      wait_barrier0();
    }
#pragma unroll
    for (int m = 0; m < 4; ++m) {
        const int rg = bm * 128 + wr * 64 + m * 16 + 4 * lg;
#pragma unroll
        for (int nn = 0; nn < 4; ++nn) {
            const int cg = bn * 128 + wc * 64 + nn * 16 + lr;
#pragma unroll
            for (int r = 0; r < 4; ++r)
                C[(size_t)(rg + r) * N + cg] = acc[m][nn][r];
        }
    }
}

// ---------------------------------------------------------------------------
// Causal flash attention (R14 version, best measured): K ring-2 + V ring-3
// = 40KB LDS -> 4 blocks/CU. Q-rope fused at register Q load. Row-sum l via
// MFMA ones-trick (Lacc[0] = full row-sum). Zero-VALU staging, P in
// registers (kappa vt), defer-max, unroll x6 static.
// ---------------------------------------------------------------------------
__global__ __launch_bounds__(256) void attn_kernel(const __bf16* __restrict__ qkp,
                                                   const __bf16* __restrict__ vt,
                                                   const float2* __restrict__ csin,
                                                   __bf16* __restrict__ attn_out) {
    const int bid = blockIdx.x;                      // 1024 blocks
    const int j = bid >> 3;                          // 0..127 per XCD
    const int bh = 2 * (bid & 7) + (j & 1);
    const int qt = 63 - (j >> 1);                    // heavy blocks first
    const int b = bh >> 3, h = bh & 7;
    const int tid = threadIdx.x;
    const int w = tid >> 6, l = tid & 63, lg = l >> 4, lr = l & 15;

    __shared__ __align__(16) __bf16 Ks[2][64 * 64];
    __shared__ __align__(16) __bf16 Vs[3][64 * 64];

    const __bf16* qbase = qkp + (size_t)b * 4096 * 1024 + h * 64;
    const __bf16* kbase = qbase + 512;
    const __bf16* vtb   = vt + (size_t)(b * 8 + h) * 64 * 4096;

    const int sr = tid >> 3;
    const int sc = ((tid & 7) ^ (sr & 7)) * 8;
    const __bf16* kp = kbase + (size_t)sr * 1024 + sc;
    const __bf16* vp = vtb + (size_t)sr * 4096 + sc;

    const int xel = (lr & 7) * 8;                    // read-side swizzle

    const int wq0 = qt * 64 + 16 * w;
    const int nkt = qt + 1;

    auto stage2 = [&](__bf16* kdst, __bf16* vdst) {
        gload16(kdst + tid * 8,         kp);
        gload16(kdst + (tid + 256) * 8, kp + 32 * 1024);
        gload16(vdst + tid * 8,         vp);
        gload16(vdst + (tid + 256) * 8, vp + 32 * 4096);
        kp += 64 * 1024;
        vp += 64;
    };

    // prologue part 1: stage tiles 0,1 (fly under Q-rope VALU)
    stage2(Ks[0], Vs[0]);
    stage2(Ks[1], Vs[1]);

    // Q load + fused rope (+ 1/sqrt(d) * log2e)
    bf16x8 Qf[2];
    {
        const __bf16* qp = qbase + (size_t)(wq0 + lr) * 1024 + 8 * lg;
        const bf16x8 rq0 = *reinterpret_cast<const bf16x8*>(qp);
        const bf16x8 rq1 = *reinterpret_cast<const bf16x8*>(qp + 32);
        const float2* csp = csin + (size_t)(wq0 + lr) * 64 + 8 * lg;
        const float qs = 0.125f * LOG2E;
#pragma unroll
        for (int i = 0; i < 8; ++i) {
            const float2 ca = csp[i];
            const float2 cb = csp[i + 32];
            const float a = (float)rq0[i], b2 = (float)rq1[i];
            Qf[0][i] = (__bf16)((a * ca.x - b2 * ca.y) * qs);
            Qf[1][i] = (__bf16)((b2 * cb.x + a * cb.y) * qs);
        }
    }

    bf16x8 ones;
#pragma unroll
    for (int i = 0; i < 8; ++i) ones[i] = (__bf16)1.0f;

    f32x4 O[4] = {};
    f32x4 Lacc = {};
    float m_ = -1e30f;

    auto qk_step = [&](f32x4 (&S)[4], const __bf16* kb) {
        __builtin_amdgcn_s_setprio(1);
#pragma unroll
        for (int jt = 0; jt < 4; ++jt) {
            const __bf16* kr = kb + (16 * jt + lr) * 64;
            const bf16x8 Kf0 = *reinterpret_cast<const bf16x8*>(kr + ((8 * lg) ^ xel));
            const bf16x8 Kf1 = *reinterpret_cast<const bf16x8*>(kr + ((32 + 8 * lg) ^ xel));
            f32x4 z = {};
            z = __builtin_amdgcn_mfma_f32_16x16x32_bf16(Kf0, Qf[0], z, 0, 0, 0);
            S[jt] = __builtin_amdgcn_mfma_f32_16x16x32_bf16(Kf1, Qf[1], z, 0, 0, 0);
        }
        __builtin_amdgcn_s_setprio(0);
    };
    auto smpv = [&](f32x4 (&SC)[4], const __bf16* vb, bool domask) {
        if (domask) {
#pragma unroll
            for (int jt = 0; jt < 4; ++jt)
#pragma unroll
                for (int r = 0; r < 4; ++r)
                    if (16 * jt + 4 * lg + r > 16 * w + lr) SC[jt][r] = -1e30f;
        }
        float mx = -1e30f;
#pragma unroll
        for (int jt = 0; jt < 4; ++jt)
            mx = fmaxf(mx, fmaxf(fmaxf(SC[jt][0], SC[jt][1]), fmaxf(SC[jt][2], SC[jt][3])));
        if (__any(mx > m_ + 8.0f)) {
            mx = fmaxf(mx, __shfl_xor(mx, 16));
            mx = fmaxf(mx, __shfl_xor(mx, 32));
            const float mn = fmaxf(m_, mx);
            const float alpha = __builtin_amdgcn_exp2f(m_ - mn);
            m_ = mn;
            Lacc *= alpha;
#pragma unroll
            for (int dt = 0; dt < 4; ++dt) O[dt] *= alpha;
        }
#pragma unroll
        for (int jt = 0; jt < 4; ++jt)
#pragma unroll
            for (int r = 0; r < 4; ++r)
                SC[jt][r] = __builtin_amdgcn_exp2f(SC[jt][r] - m_);
        __builtin_amdgcn_s_setprio(1);
#pragma unroll
        for (int s = 0; s < 2; ++s) {
            bf16x8 Pf;
#pragma unroll
            for (int i = 0; i < 8; ++i)
                Pf[i] = (__bf16)SC[2 * s + (i >> 2)][i & 3];
            Lacc = __builtin_amdgcn_mfma_f32_16x16x32_bf16(ones, Pf, Lacc, 0, 0, 0);
#pragma unroll
            for (int dt = 0; dt < 4; ++dt) {
                const bf16x8 Vf = *reinterpret_cast<const bf16x8*>(
                    vb + (16 * dt + lr) * 64 + ((32 * s + 8 * lg) ^ xel));
                O[dt] = __builtin_amdgcn_mfma_f32_16x16x32_bf16(Vf, Pf, O[dt], 0, 0, 0);
            }
        }
        __builtin_amdgcn_s_setprio(0);
    };

    f32x4 S0[4], S1[4];
    int t = 0;

    // prologue part 2: tiles 0,1 landed; S0 = QK(0); extra barrier so the
    // first loop body may overwrite Ks[0] (K ring-2 hazard).
    __syncthreads();
    qk_step(S0, Ks[0]);
    __syncthreads();

    // main loop: 6 statically-indexed bodies (K parity 2, V ring 3, S parity 2)
    for (; t + 8 <= nkt; t += 6) {
        stage2(Ks[0], Vs[2]); qk_step(S1, Ks[1]); smpv(S0, Vs[0], false); __syncthreads();
        stage2(Ks[1], Vs[0]); qk_step(S0, Ks[0]); smpv(S1, Vs[1], false); __syncthreads();
        stage2(Ks[0], Vs[1]); qk_step(S1, Ks[1]); smpv(S0, Vs[2], false); __syncthreads();
        stage2(Ks[1], Vs[2]); qk_step(S0, Ks[0]); smpv(S1, Vs[0], false); __syncthreads();
        stage2(Ks[0], Vs[0]); qk_step(S1, Ks[1]); smpv(S0, Vs[1], false); __syncthreads();
        stage2(Ks[1], Vs[1]); qk_step(S0, Ks[0]); smpv(S1, Vs[2], false); __syncthreads();
    }

    // tail: <=7 tiles, dynamic indices, mask on the last tile
    {
        f32x4 Sp[4];
#pragma unroll
        for (int jt = 0; jt < 4; ++jt) Sp[jt] = S0[jt];
        for (; t < nkt; ++t) {
            if (t + 2 < nkt) stage2(Ks[(t + 2) & 1], Vs[(t + 2) % 3]);
            f32x4 Sn[4];
            if (t + 1 < nkt) qk_step(Sn, Ks[(t + 1) & 1]);
            smpv(Sp, Vs[t % 3], t == nkt - 1);
            __syncthreads();
#pragma unroll
            for (int jt = 0; jt < 4; ++jt) Sp[jt] = Sn[jt];
        }
    }

    // epilogue: Lacc[0] is already the full row-sum (MFMA cross-lane reduce)
    const float inv = 1.0f / Lacc[0];
    __bf16* op = attn_out + ((size_t)b * 4096 + wq0 + lr) * 512 + h * 64;
#pragma unroll
    for (int dt = 0; dt < 4; ++dt) {
        union { __bf16 h4[4]; uint2 u; } ow;
#pragma unroll
        for (int r = 0; r < 4; ++r) ow.h4[r] = (__bf16)(O[dt][r] * inv);
        *reinterpret_cast<uint2*>(op + 16 * dt + 4 * lg) = ow.u;
    }
}

// ---------------------------------------------------------------------------
extern "C" void kernel_launch(void* const* d_in, const int* in_sizes, int n_in,
                              void* d_out, int out_size, void* d_ws, size_t ws_size,
                              hipStream_t stream) {
    (void)in_sizes; (void)n_in; (void)out_size; (void)ws_size;
    const float* x    = (const float*)d_in[0];
    const float* rot  = (const float*)d_in[1];
    const float* rmsw = (const float*)d_in[2];
    const float* wqkv = (const float*)d_in[3];
    const float* wout = (const float*)d_in[4];
    float* out = (float*)d_out;

    char* ws = (char*)d_ws;
    __bf16* xn    = (__bf16*)ws;                       // 16,777,216 B
    __bf16* wqkvt = (__bf16*)(ws + 16777216);          //  3,145,728 B
    __bf16* woutt = (__bf16*)(ws + 16777216 + 3145728);//  1,048,576 B
    __bf16* aout  = (__bf16*)(ws + 16777216 + 3145728 + 1048576); // 8,388,608 B
    // d_out during pipeline: qk [0,16.78M), csin [16.78M,18.87M),
    // vt [18.87M,27.26M) — all dead before the final GEMM overwrites d_out.
    __bf16* qk   = (__bf16*)d_out;
    float2* csin = (float2*)((char*)d_out + 16777216);
    __bf16* vt   = (__bf16*)((char*)d_out + 18874368);

    rmsnorm_kernel<<<8192, 256, 0, stream>>>(x, rmsw, xn);
    transpose_cast_kernel<<<dim3(48, 32), dim3(32, 8), 0, stream>>>(wqkv, wqkvt, 1024, 1536);
    transpose_cast_kernel<<<dim3(32, 16), dim3(32, 8), 0, stream>>>(wout, woutt, 512, 1024);
    csin_kernel<<<1024, 256, 0, stream>>>(rot, csin);
    gemm8_qkv<<<192, 512, 0, stream>>>(xn, wqkvt, qk, vt);
    rope_k_kernel<<<2048, 256, 0, stream>>>(qk, csin);
    attn_kernel<<<1024, 256, 0, stream>>>(qk, vt, csin, aout);
    gemm_out<<<512, 256, 0, stream>>>(aout, woutt, out, 8192, 1024, 512);
}